// Round 19
// baseline (110.534 us; speedup 1.0000x reference)
//
#include <hip/hip_runtime.h>
#include <math.h>

#define NN 100000
#define NE 1600000
#define DD 64
#define ED 16
#define BROWS 32                     // rows per bin
#define NBIN 3125                    // NN/BROWS
#define NBIN_PAD 3136
#define BCAP 704                     // slots per bin (mean 512, +8.5 sigma)
#define EPB 2048                     // edges per binAG block (2/thread, 1024 thr)
#define NBLKA ((NE + EPB - 1) / EPB) // 782

typedef float f32x4 __attribute__((ext_vector_type(4)));

// ws layout (4-byte words):
//   xpb    [NN*DD]     bf16   word 0          (3,200,000 words, 12.8 MB)
//   cursor [3136]      int    word 3,200,000
//   binned [3136*704]  int2   word 3,203,136  (17.7 MB)
// total ~30.5 MB

__device__ __forceinline__ unsigned short f2bf(float f) {
    unsigned int b = __float_as_uint(f);
    unsigned int r = (b + 0x7FFFu + ((b >> 16) & 1u)) >> 16;   // RNE
    return (unsigned short)r;
}

// K1: register-tiled projection (r13). Block = 128 nodes; x,W in padded LDS;
// thread owns 8 nodes x 4 outputs. Block 0 inits bin cursors.
__global__ __launch_bounds__(256) void proj_kernel(
    const float* __restrict__ x, const float* __restrict__ Wn,
    const float* __restrict__ bn, unsigned short* __restrict__ xpb,
    int* __restrict__ cursor) {
    __shared__ float xs[128][66];    // 33.8 KB
    __shared__ float ws[64][66];     // 16.9 KB
    int tid = threadIdx.x;
    if (blockIdx.x == 0) {
        for (int i = tid; i < NBIN_PAD; i += 256) cursor[i] = i * BCAP;
    }
    int n0 = blockIdx.x * 128;
    const float4* x4 = reinterpret_cast<const float4*>(x);
    const float4* Wn4 = reinterpret_cast<const float4*>(Wn);
    long limit = (long)NN * 16;
#pragma unroll
    for (int i = 0; i < 8; ++i) {    // stage x[128][64]
        int idx = tid + 256 * i;
        int row = idx >> 4, kq = idx & 15;
        long gidx = (long)n0 * 16 + idx;
        float4 v = (gidx < limit) ? x4[gidx] : make_float4(0.f, 0.f, 0.f, 0.f);
        xs[row][kq * 4 + 0] = v.x; xs[row][kq * 4 + 1] = v.y;
        xs[row][kq * 4 + 2] = v.z; xs[row][kq * 4 + 3] = v.w;
    }
#pragma unroll
    for (int i = 0; i < 4; ++i) {    // stage W[64][64]
        int idx = tid + 256 * i;
        int row = idx >> 4, kq = idx & 15;
        float4 v = Wn4[idx];
        ws[row][kq * 4 + 0] = v.x; ws[row][kq * 4 + 1] = v.y;
        ws[row][kq * 4 + 2] = v.z; ws[row][kq * 4 + 3] = v.w;
    }
    int og = tid & 15;               // outputs og*4..og*4+3
    int ng = tid >> 4;               // nodes ng*8..ng*8+7
    float acc[8][4];
    float b0 = bn[og * 4 + 0], b1 = bn[og * 4 + 1];
    float b2 = bn[og * 4 + 2], b3 = bn[og * 4 + 3];
#pragma unroll
    for (int i = 0; i < 8; ++i) {
        acc[i][0] = b0; acc[i][1] = b1; acc[i][2] = b2; acc[i][3] = b3;
    }
    __syncthreads();
#pragma unroll 4
    for (int kk = 0; kk < 32; ++kk) {
        float2 wv0 = *reinterpret_cast<const float2*>(&ws[og * 4 + 0][kk * 2]);
        float2 wv1 = *reinterpret_cast<const float2*>(&ws[og * 4 + 1][kk * 2]);
        float2 wv2 = *reinterpret_cast<const float2*>(&ws[og * 4 + 2][kk * 2]);
        float2 wv3 = *reinterpret_cast<const float2*>(&ws[og * 4 + 3][kk * 2]);
#pragma unroll
        for (int i = 0; i < 8; ++i) {
            float2 xv = *reinterpret_cast<const float2*>(&xs[ng * 8 + i][kk * 2]);
            acc[i][0] += xv.x * wv0.x + xv.y * wv0.y;
            acc[i][1] += xv.x * wv1.x + xv.y * wv1.y;
            acc[i][2] += xv.x * wv2.x + xv.y * wv2.y;
            acc[i][3] += xv.x * wv3.x + xv.y * wv3.y;
        }
    }
#pragma unroll
    for (int i = 0; i < 8; ++i) {
        int n = n0 + ng * 8 + i;
        if (n < NN) {
            ushort4 o;
            o.x = f2bf(acc[i][0]); o.y = f2bf(acc[i][1]);
            o.z = f2bf(acc[i][2]); o.w = f2bf(acc[i][3]);
            *reinterpret_cast<ushort4*>(xpb + (size_t)n * DD + og * 4) = o;
        }
    }
}

// K2 (binAG): fused gate + multisplit via TLP. 1024 threads x 2 edges:
// only 8 staging float4s/thread (fits the register budget the allocator
// tolerates) x 32 waves/CU -> ~256 loads in flight per CU. Single LDS-atomic
// pass with remembered slots; one cursor claim per (block,bin).
// Entry: w0 = (rowlocal<<24)|col, w1 = gate f32 bits.
__global__ __launch_bounds__(1024) void binAG_kernel(
    const int* __restrict__ ei, const float* __restrict__ ef,
    const float* __restrict__ We, const float* __restrict__ be,
    int* __restrict__ cursor, int2* __restrict__ binned) {
    __shared__ int cnt[NBIN_PAD];    // 12.5 KB
    __shared__ int basev[NBIN_PAD];  // 12.5 KB
    int tid = threadIdx.x;
    int e0 = blockIdx.x * EPB;
    for (int i = tid; i < NBIN_PAD; i += 1024) cnt[i] = 0;
    __syncthreads();
    int eA = e0 + tid * 2;
    bool ok = eA < NE;               // NE%2==0 -> both valid when ok
    int2 rows, cols;
    float g0 = 0.f, g1 = 0.f;
    int b0 = 0, b1 = 0, s0 = 0, s1 = 0;
    const f32x4* We4 = reinterpret_cast<const f32x4*>(We);
    f32x4 w0 = We4[0], w1 = We4[1], w2 = We4[2], w3 = We4[3];
    float bb = be[0];
    if (ok) {
        rows = *reinterpret_cast<const int2*>(ei + eA);
        cols = *reinterpret_cast<const int2*>(ei + NE + eA);
        const f32x4* p = reinterpret_cast<const f32x4*>(ef + (size_t)eA * ED);
        f32x4 f0 = p[0], f1 = p[1], f2 = p[2], f3 = p[3];
        f32x4 f4 = p[4], f5 = p[5], f6 = p[6], f7 = p[7];
        b0 = rows.x / BROWS; s0 = atomicAdd(&cnt[b0], 1);
        b1 = rows.y / BROWS; s1 = atomicAdd(&cnt[b1], 1);
#define DOT(A0, A1, A2, A3) \
        (A0[0]*w0[0] + A0[1]*w0[1] + A0[2]*w0[2] + A0[3]*w0[3] + \
         A1[0]*w1[0] + A1[1]*w1[1] + A1[2]*w1[2] + A1[3]*w1[3] + \
         A2[0]*w2[0] + A2[1]*w2[1] + A2[2]*w2[2] + A2[3]*w2[3] + \
         A3[0]*w3[0] + A3[1]*w3[1] + A3[2]*w3[2] + A3[3]*w3[3] + bb)
        g0 = 1.f / (1.f + expf(-DOT(f0, f1, f2, f3)));
        g1 = 1.f / (1.f + expf(-DOT(f4, f5, f6, f7)));
#undef DOT
    }
    __syncthreads();
    for (int i = tid; i < NBIN_PAD; i += 1024) {
        int cc = cnt[i];
        basev[i] = cc ? atomicAdd(&cursor[i], cc) : 0;
    }
    __syncthreads();
    if (ok) {
        int rl0 = rows.x - b0 * BROWS;
        int rl1 = rows.y - b1 * BROWS;
        binned[basev[b0] + s0] = make_int2((rl0 << 24) | cols.x, __float_as_int(g0));
        binned[basev[b1] + s1] = make_int2((rl1 << 24) | cols.y, __float_as_int(g1));
    }
}

// K3 (binB): one block per 32-row bin (~5.9 KB LDS -> many blocks/CU).
// Single global read (<=2 entries/thread, mostly 1), hist with remembered
// slots, 32-wide scan, register->LDS scatter, quarter-wave gather
// (16 lanes/row, uint2 = 4 bf16 ch/lane), shfl_xor reduce, float4 store.
__global__ __launch_bounds__(512) void binB_kernel(
    const unsigned short* __restrict__ xpb, const int* __restrict__ cursor,
    const int2* __restrict__ binned, float* __restrict__ out) {
    __shared__ int2 sorted[BCAP];    // 5.6 KB
    __shared__ int hist[32];
    __shared__ int offs[32];
    int tid = threadIdx.x;
    int b = blockIdx.x;
    if (tid < 32) hist[tid] = 0;
    __syncthreads();
    int bstart = b * BCAP;
    int nb = cursor[b] - bstart;     // edges in this bin (uniform, <= BCAP)
    int2 e0_, e1_;
    int r0 = 0, r1 = 0;
    int s0 = -1, s1 = -1;
    bool k0 = tid < nb, k1 = tid + 512 < nb;
    if (k0) e0_ = binned[bstart + tid];
    if (k1) e1_ = binned[bstart + tid + 512];
    if (k0) { r0 = (e0_.x >> 24) & 0x1F; s0 = atomicAdd(&hist[r0], 1); }
    if (k1) { r1 = (e1_.x >> 24) & 0x1F; s1 = atomicAdd(&hist[r1], 1); }
    __syncthreads();
    if (tid < 32) offs[tid] = hist[tid];
    __syncthreads();
    for (int d = 1; d < 32; d <<= 1) {
        int add = 0;
        if (tid < 32 && tid >= d) add = offs[tid - d];
        __syncthreads();
        if (tid < 32) offs[tid] += add;
        __syncthreads();
    }
    if (s0 >= 0) sorted[offs[r0] - hist[r0] + s0] = e0_;
    if (s1 >= 0) sorted[offs[r1] - hist[r1] + s1] = e1_;
    __syncthreads();
    int lane = tid & 63;
    int wv = tid >> 6;
    int q = lane >> 4;
    int ql = lane & 15;
#pragma unroll 1
    for (int i = 0; i < 4; ++i) {
        int rl = wv + 8 * i;
        int row = b * BROWS + rl;
        if (row >= NN) break;        // wave-uniform
        int dn = hist[rl];
        int sb = offs[rl] - dn;
        float a0 = 0.f, a1 = 0.f, a2 = 0.f, a3 = 0.f;
        for (int j = 0; j < dn; j += 16) {
#pragma unroll
            for (int k = 0; k < 4; ++k) {
                int idx = j + 4 * k + q;
                int2 e = sorted[sb + min(idx, dn - 1)];
                float g = (idx < dn) ? __int_as_float(e.y) : 0.f;
                int col = e.x & 0x1FFFF;
                uint2 u = *reinterpret_cast<const uint2*>(
                    xpb + (size_t)col * DD + ql * 4);
                a0 += g * __uint_as_float(u.x << 16);
                a1 += g * __uint_as_float(u.x & 0xFFFF0000u);
                a2 += g * __uint_as_float(u.y << 16);
                a3 += g * __uint_as_float(u.y & 0xFFFF0000u);
            }
        }
        a0 += __shfl_xor(a0, 16); a0 += __shfl_xor(a0, 32);
        a1 += __shfl_xor(a1, 16); a1 += __shfl_xor(a1, 32);
        a2 += __shfl_xor(a2, 16); a2 += __shfl_xor(a2, 32);
        a3 += __shfl_xor(a3, 16); a3 += __shfl_xor(a3, 32);
        if (q == 0) {
            float dv = fmaxf((float)dn, 1.f);
            *reinterpret_cast<float4*>(&out[(size_t)row * DD + ql * 4]) =
                make_float4(a0 / dv, a1 / dv, a2 / dv, a3 / dv);
        }
    }
}

extern "C" void kernel_launch(void* const* d_in, const int* in_sizes, int n_in,
                              void* d_out, int out_size, void* d_ws, size_t ws_size,
                              hipStream_t stream) {
    const float* x  = (const float*)d_in[0];
    const int*   ei = (const int*)d_in[1];   // [2, NE] int32
    const float* ef = (const float*)d_in[2];
    const float* We = (const float*)d_in[3];
    const float* be = (const float*)d_in[4];
    const float* Wn = (const float*)d_in[5];
    const float* bn = (const float*)d_in[6];
    float* out = (float*)d_out;

    unsigned short* xpb = (unsigned short*)d_ws;
    int*  cursor = (int*)d_ws + 3200000;
    int2* binned = (int2*)((int*)d_ws + 3203136);

    proj_kernel<<<(NN + 127) / 128, 256, 0, stream>>>(x, Wn, bn, xpb, cursor);
    binAG_kernel<<<NBLKA, 1024, 0, stream>>>(ei, ef, We, be, cursor, binned);
    binB_kernel<<<NBIN, 512, 0, stream>>>(xpb, cursor, binned, out);
}

// Round 20
// 106.457 us; speedup vs baseline: 1.0383x; 1.0383x over previous
//
#include <hip/hip_runtime.h>
#include <math.h>

#define NN 100000
#define NE 1600000
#define DD 64
#define ED 16
#define BROWS 48                     // rows per bin
#define NBIN 2084                    // ceil(NN/BROWS)
#define NBIN_PAD 2112
#define BCAP 960                     // slots per bin (mean 768, +6.9 sigma)
#define EPB 8192                     // edges per binAG block (8/thread, 1024 thr)
#define NBLKA ((NE + EPB - 1) / EPB) // 196

typedef float f32x4 __attribute__((ext_vector_type(4)));

// ws layout (4-byte words):
//   xpb    [NN*DD]     bf16   word 0          (3,200,000 words, 12.8 MB)
//   cursor [2112]      int    word 3,200,000
//   binned [2112*960]  int2   word 3,202,112  (16.2 MB)
// total ~29.4 MB

__device__ __forceinline__ unsigned short f2bf(float f) {
    unsigned int b = __float_as_uint(f);
    unsigned int r = (b + 0x7FFFu + ((b >> 16) & 1u)) >> 16;   // RNE
    return (unsigned short)r;
}

// K1: register-tiled projection (r13). Block = 128 nodes; x,W in padded LDS;
// thread owns 8 nodes x 4 outputs. Block 0 inits bin cursors.
__global__ __launch_bounds__(256) void proj_kernel(
    const float* __restrict__ x, const float* __restrict__ Wn,
    const float* __restrict__ bn, unsigned short* __restrict__ xpb,
    int* __restrict__ cursor) {
    __shared__ float xs[128][66];    // 33.8 KB
    __shared__ float ws[64][66];     // 16.9 KB
    int tid = threadIdx.x;
    if (blockIdx.x == 0) {
        for (int i = tid; i < NBIN_PAD; i += 256) cursor[i] = i * BCAP;
    }
    int n0 = blockIdx.x * 128;
    const float4* x4 = reinterpret_cast<const float4*>(x);
    const float4* Wn4 = reinterpret_cast<const float4*>(Wn);
    long limit = (long)NN * 16;
#pragma unroll
    for (int i = 0; i < 8; ++i) {    // stage x[128][64]
        int idx = tid + 256 * i;
        int row = idx >> 4, kq = idx & 15;
        long gidx = (long)n0 * 16 + idx;
        float4 v = (gidx < limit) ? x4[gidx] : make_float4(0.f, 0.f, 0.f, 0.f);
        xs[row][kq * 4 + 0] = v.x; xs[row][kq * 4 + 1] = v.y;
        xs[row][kq * 4 + 2] = v.z; xs[row][kq * 4 + 3] = v.w;
    }
#pragma unroll
    for (int i = 0; i < 4; ++i) {    // stage W[64][64]
        int idx = tid + 256 * i;
        int row = idx >> 4, kq = idx & 15;
        float4 v = Wn4[idx];
        ws[row][kq * 4 + 0] = v.x; ws[row][kq * 4 + 1] = v.y;
        ws[row][kq * 4 + 2] = v.z; ws[row][kq * 4 + 3] = v.w;
    }
    int og = tid & 15;               // outputs og*4..og*4+3
    int ng = tid >> 4;               // nodes ng*8..ng*8+7
    float acc[8][4];
    float b0 = bn[og * 4 + 0], b1 = bn[og * 4 + 1];
    float b2 = bn[og * 4 + 2], b3 = bn[og * 4 + 3];
#pragma unroll
    for (int i = 0; i < 8; ++i) {
        acc[i][0] = b0; acc[i][1] = b1; acc[i][2] = b2; acc[i][3] = b3;
    }
    __syncthreads();
#pragma unroll 4
    for (int kk = 0; kk < 32; ++kk) {
        float2 wv0 = *reinterpret_cast<const float2*>(&ws[og * 4 + 0][kk * 2]);
        float2 wv1 = *reinterpret_cast<const float2*>(&ws[og * 4 + 1][kk * 2]);
        float2 wv2 = *reinterpret_cast<const float2*>(&ws[og * 4 + 2][kk * 2]);
        float2 wv3 = *reinterpret_cast<const float2*>(&ws[og * 4 + 3][kk * 2]);
#pragma unroll
        for (int i = 0; i < 8; ++i) {
            float2 xv = *reinterpret_cast<const float2*>(&xs[ng * 8 + i][kk * 2]);
            acc[i][0] += xv.x * wv0.x + xv.y * wv0.y;
            acc[i][1] += xv.x * wv1.x + xv.y * wv1.y;
            acc[i][2] += xv.x * wv2.x + xv.y * wv2.y;
            acc[i][3] += xv.x * wv3.x + xv.y * wv3.y;
        }
    }
#pragma unroll
    for (int i = 0; i < 8; ++i) {
        int n = n0 + ng * 8 + i;
        if (n < NN) {
            ushort4 o;
            o.x = f2bf(acc[i][0]); o.y = f2bf(acc[i][1]);
            o.z = f2bf(acc[i][2]); o.w = f2bf(acc[i][3]);
            *reinterpret_cast<ushort4*>(xpb + (size_t)n * DD + og * 4) = o;
        }
    }
}

// K2 (binAG): fused gate + multisplit, 1024 thr x 8 edges (two 4-edge
// stages), EPB 8192 -> ~31B chunks per (block,bin) (2x r18's clustering).
// One cursor claim per (block,bin).
// Entry: w0 = (rowlocal<<24)|col, w1 = gate f32 bits.
__global__ __launch_bounds__(1024) void binAG_kernel(
    const int* __restrict__ ei, const float* __restrict__ ef,
    const float* __restrict__ We, const float* __restrict__ be,
    int* __restrict__ cursor, int2* __restrict__ binned) {
    __shared__ int cnt[NBIN_PAD];
    __shared__ int basev[NBIN_PAD];
    int tid = threadIdx.x;
    long e0 = (long)blockIdx.x * EPB;
    for (int i = tid; i < NBIN_PAD; i += 1024) cnt[i] = 0;
    __syncthreads();
    long eA = e0 + tid * 8;
    bool ok = eA < NE;               // NE%8==0 -> all 8 valid when ok
    int4 rA, rB, cA, cB;
    float g0=0,g1=0,g2=0,g3=0,g4=0,g5=0,g6=0,g7=0;
    int b0=0,b1=0,b2=0,b3=0,b4=0,b5=0,b6=0,b7=0;
    int s0=0,s1=0,s2=0,s3=0,s4=0,s5=0,s6=0,s7=0;
    const f32x4* We4 = reinterpret_cast<const f32x4*>(We);
    f32x4 w0 = We4[0], w1 = We4[1], w2 = We4[2], w3 = We4[3];
    float bb = be[0];
    if (ok) {
        rA = *reinterpret_cast<const int4*>(ei + eA);
        rB = *reinterpret_cast<const int4*>(ei + eA + 4);
        cA = *reinterpret_cast<const int4*>(ei + NE + eA);
        cB = *reinterpret_cast<const int4*>(ei + NE + eA + 4);
        const f32x4* p = reinterpret_cast<const f32x4*>(ef + eA * ED);
#define DOT(A0, A1, A2, A3) \
        (A0[0]*w0[0] + A0[1]*w0[1] + A0[2]*w0[2] + A0[3]*w0[3] + \
         A1[0]*w1[0] + A1[1]*w1[1] + A1[2]*w1[2] + A1[3]*w1[3] + \
         A2[0]*w2[0] + A2[1]*w2[1] + A2[2]*w2[2] + A2[3]*w2[3] + \
         A3[0]*w3[0] + A3[1]*w3[1] + A3[2]*w3[2] + A3[3]*w3[3] + bb)
        {   // stage A: edges 0..3
            f32x4 f0 = p[0],  f1 = p[1],  f2 = p[2],  f3 = p[3];
            f32x4 f4 = p[4],  f5 = p[5],  f6 = p[6],  f7 = p[7];
            f32x4 f8 = p[8],  f9 = p[9],  fa = p[10], fb = p[11];
            f32x4 fc = p[12], fd = p[13], fe = p[14], ff = p[15];
            asm volatile("" ::
                "v"(f0), "v"(f1), "v"(f2), "v"(f3),
                "v"(f4), "v"(f5), "v"(f6), "v"(f7),
                "v"(f8), "v"(f9), "v"(fa), "v"(fb),
                "v"(fc), "v"(fd), "v"(fe), "v"(ff));
            b0 = rA.x / BROWS; s0 = atomicAdd(&cnt[b0], 1);
            b1 = rA.y / BROWS; s1 = atomicAdd(&cnt[b1], 1);
            b2 = rA.z / BROWS; s2 = atomicAdd(&cnt[b2], 1);
            b3 = rA.w / BROWS; s3 = atomicAdd(&cnt[b3], 1);
            g0 = 1.f / (1.f + expf(-DOT(f0, f1, f2, f3)));
            g1 = 1.f / (1.f + expf(-DOT(f4, f5, f6, f7)));
            g2 = 1.f / (1.f + expf(-DOT(f8, f9, fa, fb)));
            g3 = 1.f / (1.f + expf(-DOT(fc, fd, fe, ff)));
        }
        {   // stage B: edges 4..7
            f32x4 f0 = p[16], f1 = p[17], f2 = p[18], f3 = p[19];
            f32x4 f4 = p[20], f5 = p[21], f6 = p[22], f7 = p[23];
            f32x4 f8 = p[24], f9 = p[25], fa = p[26], fb = p[27];
            f32x4 fc = p[28], fd = p[29], fe = p[30], ff = p[31];
            asm volatile("" ::
                "v"(f0), "v"(f1), "v"(f2), "v"(f3),
                "v"(f4), "v"(f5), "v"(f6), "v"(f7),
                "v"(f8), "v"(f9), "v"(fa), "v"(fb),
                "v"(fc), "v"(fd), "v"(fe), "v"(ff));
            b4 = rB.x / BROWS; s4 = atomicAdd(&cnt[b4], 1);
            b5 = rB.y / BROWS; s5 = atomicAdd(&cnt[b5], 1);
            b6 = rB.z / BROWS; s6 = atomicAdd(&cnt[b6], 1);
            b7 = rB.w / BROWS; s7 = atomicAdd(&cnt[b7], 1);
            g4 = 1.f / (1.f + expf(-DOT(f0, f1, f2, f3)));
            g5 = 1.f / (1.f + expf(-DOT(f4, f5, f6, f7)));
            g6 = 1.f / (1.f + expf(-DOT(f8, f9, fa, fb)));
            g7 = 1.f / (1.f + expf(-DOT(fc, fd, fe, ff)));
        }
#undef DOT
    }
    __syncthreads();
    for (int i = tid; i < NBIN_PAD; i += 1024) {
        int cc = cnt[i];
        basev[i] = cc ? atomicAdd(&cursor[i], cc) : 0;
    }
    __syncthreads();
    if (ok) {
#define EMIT(BV, SV, RR, CC, GG) \
        binned[basev[BV] + SV] = \
            make_int2((((RR) - (BV) * BROWS) << 24) | (CC), __float_as_int(GG));
        EMIT(b0, s0, rA.x, cA.x, g0) EMIT(b1, s1, rA.y, cA.y, g1)
        EMIT(b2, s2, rA.z, cA.z, g2) EMIT(b3, s3, rA.w, cA.w, g3)
        EMIT(b4, s4, rB.x, cB.x, g4) EMIT(b5, s5, rB.y, cB.y, g5)
        EMIT(b6, s6, rB.z, cB.z, g6) EMIT(b7, s7, rB.w, cB.w, g7)
#undef EMIT
    }
}

// K3 (binB): one block per 48-row bin (~8 KB LDS -> high blocks/CU, short
// tail). Single global read (<=2 entries/thread), hist with remembered
// slots, 64-wide scan, register->LDS scatter, quarter-wave gather
// (16 lanes/row, uint2 = 4 bf16 ch/lane), shfl_xor reduce, float4 store.
__global__ __launch_bounds__(512) void binB_kernel(
    const unsigned short* __restrict__ xpb, const int* __restrict__ cursor,
    const int2* __restrict__ binned, float* __restrict__ out) {
    __shared__ int2 sorted[BCAP];    // 7.7 KB
    __shared__ int hist[64];
    __shared__ int offs[64];
    int tid = threadIdx.x;
    int b = blockIdx.x;
    if (tid < 64) hist[tid] = 0;
    __syncthreads();
    int bstart = b * BCAP;
    int nb = cursor[b] - bstart;     // edges in this bin (uniform, <= BCAP)
    int2 e0_, e1_;
    int r0 = 0, r1 = 0;
    int s0 = -1, s1 = -1;
    bool k0 = tid < nb, k1 = tid + 512 < nb;
    if (k0) e0_ = binned[bstart + tid];
    if (k1) e1_ = binned[bstart + tid + 512];
    if (k0) { r0 = (e0_.x >> 24) & 0x3F; s0 = atomicAdd(&hist[r0], 1); }
    if (k1) { r1 = (e1_.x >> 24) & 0x3F; s1 = atomicAdd(&hist[r1], 1); }
    __syncthreads();
    if (tid < 64) offs[tid] = hist[tid];
    __syncthreads();
    for (int d = 1; d < 64; d <<= 1) {
        int add = 0;
        if (tid < 64 && tid >= d) add = offs[tid - d];
        __syncthreads();
        if (tid < 64) offs[tid] += add;
        __syncthreads();
    }
    if (s0 >= 0) sorted[offs[r0] - hist[r0] + s0] = e0_;
    if (s1 >= 0) sorted[offs[r1] - hist[r1] + s1] = e1_;
    __syncthreads();
    int lane = tid & 63;
    int wv = tid >> 6;
    int q = lane >> 4;
    int ql = lane & 15;
#pragma unroll 1
    for (int i = 0; i < 6; ++i) {
        int rl = wv + 8 * i;
        int row = b * BROWS + rl;
        if (row >= NN) break;        // wave-uniform
        int dn = hist[rl];
        int sb = offs[rl] - dn;
        float a0 = 0.f, a1 = 0.f, a2 = 0.f, a3 = 0.f;
        for (int j = 0; j < dn; j += 16) {
#pragma unroll
            for (int k = 0; k < 4; ++k) {
                int idx = j + 4 * k + q;
                int2 e = sorted[sb + min(idx, dn - 1)];
                float g = (idx < dn) ? __int_as_float(e.y) : 0.f;
                int col = e.x & 0x1FFFF;
                uint2 u = *reinterpret_cast<const uint2*>(
                    xpb + (size_t)col * DD + ql * 4);
                a0 += g * __uint_as_float(u.x << 16);
                a1 += g * __uint_as_float(u.x & 0xFFFF0000u);
                a2 += g * __uint_as_float(u.y << 16);
                a3 += g * __uint_as_float(u.y & 0xFFFF0000u);
            }
        }
        a0 += __shfl_xor(a0, 16); a0 += __shfl_xor(a0, 32);
        a1 += __shfl_xor(a1, 16); a1 += __shfl_xor(a1, 32);
        a2 += __shfl_xor(a2, 16); a2 += __shfl_xor(a2, 32);
        a3 += __shfl_xor(a3, 16); a3 += __shfl_xor(a3, 32);
        if (q == 0) {
            float dv = fmaxf((float)dn, 1.f);
            *reinterpret_cast<float4*>(&out[(size_t)row * DD + ql * 4]) =
                make_float4(a0 / dv, a1 / dv, a2 / dv, a3 / dv);
        }
    }
}

extern "C" void kernel_launch(void* const* d_in, const int* in_sizes, int n_in,
                              void* d_out, int out_size, void* d_ws, size_t ws_size,
                              hipStream_t stream) {
    const float* x  = (const float*)d_in[0];
    const int*   ei = (const int*)d_in[1];   // [2, NE] int32
    const float* ef = (const float*)d_in[2];
    const float* We = (const float*)d_in[3];
    const float* be = (const float*)d_in[4];
    const float* Wn = (const float*)d_in[5];
    const float* bn = (const float*)d_in[6];
    float* out = (float*)d_out;

    unsigned short* xpb = (unsigned short*)d_ws;
    int*  cursor = (int*)d_ws + 3200000;
    int2* binned = (int2*)((int*)d_ws + 3202112);

    proj_kernel<<<(NN + 127) / 128, 256, 0, stream>>>(x, Wn, bn, xpb, cursor);
    binAG_kernel<<<NBLKA, 1024, 0, stream>>>(ei, ef, We, be, cursor, binned);
    binB_kernel<<<NBIN, 512, 0, stream>>>(xpb, cursor, binned, out);
}

// Round 21
// 104.408 us; speedup vs baseline: 1.0587x; 1.0196x over previous
//
#include <hip/hip_runtime.h>
#include <math.h>

#define NN 100000
#define NE 1600000
#define DD 64
#define ED 16
#define BROWS 48                     // rows per bin
#define NBIN 2084                    // ceil(NN/BROWS)
#define NBIN_PAD 2112
#define BCAP 960                     // slots per bin (mean 768, +6.9 sigma)
#define EPB 4096                     // edges per binAG block (8/thread, 512 thr)
#define NBLKA ((NE + EPB - 1) / EPB) // 391

typedef float f32x4 __attribute__((ext_vector_type(4)));

// ws layout (4-byte words):
//   xpb    [NN*DD]     bf16   word 0          (3,200,000 words, 12.8 MB)
//   cursor [2112]      int    word 3,200,000
//   binned [2112*960]  int2   word 3,202,112  (16.2 MB)
// total ~29.4 MB

__device__ __forceinline__ unsigned short f2bf(float f) {
    unsigned int b = __float_as_uint(f);
    unsigned int r = (b + 0x7FFFu + ((b >> 16) & 1u)) >> 16;   // RNE
    return (unsigned short)r;
}

// K1: register-tiled projection (r13). Block = 128 nodes; x,W in padded LDS;
// thread owns 8 nodes x 4 outputs. Block 0 inits bin cursors.
__global__ __launch_bounds__(256) void proj_kernel(
    const float* __restrict__ x, const float* __restrict__ Wn,
    const float* __restrict__ bn, unsigned short* __restrict__ xpb,
    int* __restrict__ cursor) {
    __shared__ float xs[128][66];    // 33.8 KB
    __shared__ float ws[64][66];     // 16.9 KB
    int tid = threadIdx.x;
    if (blockIdx.x == 0) {
        for (int i = tid; i < NBIN_PAD; i += 256) cursor[i] = i * BCAP;
    }
    int n0 = blockIdx.x * 128;
    const float4* x4 = reinterpret_cast<const float4*>(x);
    const float4* Wn4 = reinterpret_cast<const float4*>(Wn);
    long limit = (long)NN * 16;
#pragma unroll
    for (int i = 0; i < 8; ++i) {    // stage x[128][64]
        int idx = tid + 256 * i;
        int row = idx >> 4, kq = idx & 15;
        long gidx = (long)n0 * 16 + idx;
        float4 v = (gidx < limit) ? x4[gidx] : make_float4(0.f, 0.f, 0.f, 0.f);
        xs[row][kq * 4 + 0] = v.x; xs[row][kq * 4 + 1] = v.y;
        xs[row][kq * 4 + 2] = v.z; xs[row][kq * 4 + 3] = v.w;
    }
#pragma unroll
    for (int i = 0; i < 4; ++i) {    // stage W[64][64]
        int idx = tid + 256 * i;
        int row = idx >> 4, kq = idx & 15;
        float4 v = Wn4[idx];
        ws[row][kq * 4 + 0] = v.x; ws[row][kq * 4 + 1] = v.y;
        ws[row][kq * 4 + 2] = v.z; ws[row][kq * 4 + 3] = v.w;
    }
    int og = tid & 15;               // outputs og*4..og*4+3
    int ng = tid >> 4;               // nodes ng*8..ng*8+7
    float acc[8][4];
    float b0 = bn[og * 4 + 0], b1 = bn[og * 4 + 1];
    float b2 = bn[og * 4 + 2], b3 = bn[og * 4 + 3];
#pragma unroll
    for (int i = 0; i < 8; ++i) {
        acc[i][0] = b0; acc[i][1] = b1; acc[i][2] = b2; acc[i][3] = b3;
    }
    __syncthreads();
#pragma unroll 4
    for (int kk = 0; kk < 32; ++kk) {
        float2 wv0 = *reinterpret_cast<const float2*>(&ws[og * 4 + 0][kk * 2]);
        float2 wv1 = *reinterpret_cast<const float2*>(&ws[og * 4 + 1][kk * 2]);
        float2 wv2 = *reinterpret_cast<const float2*>(&ws[og * 4 + 2][kk * 2]);
        float2 wv3 = *reinterpret_cast<const float2*>(&ws[og * 4 + 3][kk * 2]);
#pragma unroll
        for (int i = 0; i < 8; ++i) {
            float2 xv = *reinterpret_cast<const float2*>(&xs[ng * 8 + i][kk * 2]);
            acc[i][0] += xv.x * wv0.x + xv.y * wv0.y;
            acc[i][1] += xv.x * wv1.x + xv.y * wv1.y;
            acc[i][2] += xv.x * wv2.x + xv.y * wv2.y;
            acc[i][3] += xv.x * wv3.x + xv.y * wv3.y;
        }
    }
#pragma unroll
    for (int i = 0; i < 8; ++i) {
        int n = n0 + ng * 8 + i;
        if (n < NN) {
            ushort4 o;
            o.x = f2bf(acc[i][0]); o.y = f2bf(acc[i][1]);
            o.z = f2bf(acc[i][2]); o.w = f2bf(acc[i][3]);
            *reinterpret_cast<ushort4*>(xpb + (size_t)n * DD + og * 4) = o;
        }
    }
}

// K2 (binAG): fused gate + multisplit, 512 thr x 8 edges (two 4-edge stages),
// r16/r18 structure (asm MLP barrier). One cursor claim per (block,bin).
// Entry: w0 = (rowlocal<<24)|col, w1 = gate f32 bits.
__global__ __launch_bounds__(512, 2) void binAG_kernel(
    const int* __restrict__ ei, const float* __restrict__ ef,
    const float* __restrict__ We, const float* __restrict__ be,
    int* __restrict__ cursor, int2* __restrict__ binned) {
    __shared__ int cnt[NBIN_PAD];
    __shared__ int basev[NBIN_PAD];
    int tid = threadIdx.x;
    long e0 = (long)blockIdx.x * EPB;
    for (int i = tid; i < NBIN_PAD; i += 512) cnt[i] = 0;
    __syncthreads();
    long eA = e0 + tid * 8;
    bool ok = eA < NE;               // NE%8==0 -> all 8 valid when ok
    int4 rA, rB, cA, cB;
    float g0=0,g1=0,g2=0,g3=0,g4=0,g5=0,g6=0,g7=0;
    int b0=0,b1=0,b2=0,b3=0,b4=0,b5=0,b6=0,b7=0;
    int s0=0,s1=0,s2=0,s3=0,s4=0,s5=0,s6=0,s7=0;
    const f32x4* We4 = reinterpret_cast<const f32x4*>(We);
    f32x4 w0 = We4[0], w1 = We4[1], w2 = We4[2], w3 = We4[3];
    float bb = be[0];
    if (ok) {
        rA = *reinterpret_cast<const int4*>(ei + eA);
        rB = *reinterpret_cast<const int4*>(ei + eA + 4);
        cA = *reinterpret_cast<const int4*>(ei + NE + eA);
        cB = *reinterpret_cast<const int4*>(ei + NE + eA + 4);
        const f32x4* p = reinterpret_cast<const f32x4*>(ef + eA * ED);
#define DOT(A0, A1, A2, A3) \
        (A0[0]*w0[0] + A0[1]*w0[1] + A0[2]*w0[2] + A0[3]*w0[3] + \
         A1[0]*w1[0] + A1[1]*w1[1] + A1[2]*w1[2] + A1[3]*w1[3] + \
         A2[0]*w2[0] + A2[1]*w2[1] + A2[2]*w2[2] + A2[3]*w2[3] + \
         A3[0]*w3[0] + A3[1]*w3[1] + A3[2]*w3[2] + A3[3]*w3[3] + bb)
        {   // stage A: edges 0..3
            f32x4 f0 = p[0],  f1 = p[1],  f2 = p[2],  f3 = p[3];
            f32x4 f4 = p[4],  f5 = p[5],  f6 = p[6],  f7 = p[7];
            f32x4 f8 = p[8],  f9 = p[9],  fa = p[10], fb = p[11];
            f32x4 fc = p[12], fd = p[13], fe = p[14], ff = p[15];
            asm volatile("" ::
                "v"(f0), "v"(f1), "v"(f2), "v"(f3),
                "v"(f4), "v"(f5), "v"(f6), "v"(f7),
                "v"(f8), "v"(f9), "v"(fa), "v"(fb),
                "v"(fc), "v"(fd), "v"(fe), "v"(ff));
            b0 = rA.x / BROWS; s0 = atomicAdd(&cnt[b0], 1);
            b1 = rA.y / BROWS; s1 = atomicAdd(&cnt[b1], 1);
            b2 = rA.z / BROWS; s2 = atomicAdd(&cnt[b2], 1);
            b3 = rA.w / BROWS; s3 = atomicAdd(&cnt[b3], 1);
            g0 = 1.f / (1.f + expf(-DOT(f0, f1, f2, f3)));
            g1 = 1.f / (1.f + expf(-DOT(f4, f5, f6, f7)));
            g2 = 1.f / (1.f + expf(-DOT(f8, f9, fa, fb)));
            g3 = 1.f / (1.f + expf(-DOT(fc, fd, fe, ff)));
        }
        {   // stage B: edges 4..7
            f32x4 f0 = p[16], f1 = p[17], f2 = p[18], f3 = p[19];
            f32x4 f4 = p[20], f5 = p[21], f6 = p[22], f7 = p[23];
            f32x4 f8 = p[24], f9 = p[25], fa = p[26], fb = p[27];
            f32x4 fc = p[28], fd = p[29], fe = p[30], ff = p[31];
            asm volatile("" ::
                "v"(f0), "v"(f1), "v"(f2), "v"(f3),
                "v"(f4), "v"(f5), "v"(f6), "v"(f7),
                "v"(f8), "v"(f9), "v"(fa), "v"(fb),
                "v"(fc), "v"(fd), "v"(fe), "v"(ff));
            b4 = rB.x / BROWS; s4 = atomicAdd(&cnt[b4], 1);
            b5 = rB.y / BROWS; s5 = atomicAdd(&cnt[b5], 1);
            b6 = rB.z / BROWS; s6 = atomicAdd(&cnt[b6], 1);
            b7 = rB.w / BROWS; s7 = atomicAdd(&cnt[b7], 1);
            g4 = 1.f / (1.f + expf(-DOT(f0, f1, f2, f3)));
            g5 = 1.f / (1.f + expf(-DOT(f4, f5, f6, f7)));
            g6 = 1.f / (1.f + expf(-DOT(f8, f9, fa, fb)));
            g7 = 1.f / (1.f + expf(-DOT(fc, fd, fe, ff)));
        }
#undef DOT
    }
    __syncthreads();
    for (int i = tid; i < NBIN_PAD; i += 512) {
        int cc = cnt[i];
        basev[i] = cc ? atomicAdd(&cursor[i], cc) : 0;
    }
    __syncthreads();
    if (ok) {
#define EMIT(BV, SV, RR, CC, GG) \
        binned[basev[BV] + SV] = \
            make_int2((((RR) - (BV) * BROWS) << 24) | (CC), __float_as_int(GG));
        EMIT(b0, s0, rA.x, cA.x, g0) EMIT(b1, s1, rA.y, cA.y, g1)
        EMIT(b2, s2, rA.z, cA.z, g2) EMIT(b3, s3, rA.w, cA.w, g3)
        EMIT(b4, s4, rB.x, cB.x, g4) EMIT(b5, s5, rB.y, cB.y, g5)
        EMIT(b6, s6, rB.z, cB.z, g6) EMIT(b7, s7, rB.w, cB.w, g7)
#undef EMIT
    }
}

// K3 (binB): one block per 48-row bin. Single global read, hist with
// remembered slots, 64-wide scan, register->LDS scatter. Gather: UNCLAMPED
// full 16-entry trips (no min/cmp/cndmask, no wasted gathers) + one clamped
// tail trip only when dn%16 != 0; empty rows short-circuit.
__global__ __launch_bounds__(512) void binB_kernel(
    const unsigned short* __restrict__ xpb, const int* __restrict__ cursor,
    const int2* __restrict__ binned, float* __restrict__ out) {
    __shared__ int2 sorted[BCAP];    // 7.7 KB
    __shared__ int hist[64];
    __shared__ int offs[64];
    int tid = threadIdx.x;
    int b = blockIdx.x;
    if (tid < 64) hist[tid] = 0;
    __syncthreads();
    int bstart = b * BCAP;
    int nb = cursor[b] - bstart;     // edges in this bin (uniform, <= BCAP)
    int2 e0_, e1_;
    int r0 = 0, r1 = 0;
    int s0 = -1, s1 = -1;
    bool k0 = tid < nb, k1 = tid + 512 < nb;
    if (k0) e0_ = binned[bstart + tid];
    if (k1) e1_ = binned[bstart + tid + 512];
    if (k0) { r0 = (e0_.x >> 24) & 0x3F; s0 = atomicAdd(&hist[r0], 1); }
    if (k1) { r1 = (e1_.x >> 24) & 0x3F; s1 = atomicAdd(&hist[r1], 1); }
    __syncthreads();
    if (tid < 64) offs[tid] = hist[tid];
    __syncthreads();
    for (int d = 1; d < 64; d <<= 1) {
        int add = 0;
        if (tid < 64 && tid >= d) add = offs[tid - d];
        __syncthreads();
        if (tid < 64) offs[tid] += add;
        __syncthreads();
    }
    if (s0 >= 0) sorted[offs[r0] - hist[r0] + s0] = e0_;
    if (s1 >= 0) sorted[offs[r1] - hist[r1] + s1] = e1_;
    __syncthreads();
    int lane = tid & 63;
    int wv = tid >> 6;
    int q = lane >> 4;
    int ql = lane & 15;
#pragma unroll 1
    for (int i = 0; i < 6; ++i) {
        int rl = wv + 8 * i;
        int row = b * BROWS + rl;
        if (row >= NN) break;        // wave-uniform
        int dn = hist[rl];
        int sb = offs[rl] - dn;
        float a0 = 0.f, a1 = 0.f, a2 = 0.f, a3 = 0.f;
        int nfull = dn & ~15;        // full 16-entry trips (wave-uniform)
        int j = 0;
#pragma unroll 1
        for (; j < nfull; j += 16) { // unclamped: no min, no predicate
#pragma unroll
            for (int k = 0; k < 4; ++k) {
                int2 e = sorted[sb + j + 4 * k + q];
                float g = __int_as_float(e.y);
                int col = e.x & 0x1FFFF;
                uint2 u = *reinterpret_cast<const uint2*>(
                    xpb + (size_t)col * DD + ql * 4);
                a0 += g * __uint_as_float(u.x << 16);
                a1 += g * __uint_as_float(u.x & 0xFFFF0000u);
                a2 += g * __uint_as_float(u.y << 16);
                a3 += g * __uint_as_float(u.y & 0xFFFF0000u);
            }
        }
        if (j < dn) {                // single clamped tail trip
#pragma unroll
            for (int k = 0; k < 4; ++k) {
                int idx = j + 4 * k + q;
                int2 e = sorted[sb + min(idx, dn - 1)];
                float g = (idx < dn) ? __int_as_float(e.y) : 0.f;
                int col = e.x & 0x1FFFF;
                uint2 u = *reinterpret_cast<const uint2*>(
                    xpb + (size_t)col * DD + ql * 4);
                a0 += g * __uint_as_float(u.x << 16);
                a1 += g * __uint_as_float(u.x & 0xFFFF0000u);
                a2 += g * __uint_as_float(u.y << 16);
                a3 += g * __uint_as_float(u.y & 0xFFFF0000u);
            }
        }
        if (dn > 0) {
            a0 += __shfl_xor(a0, 16); a0 += __shfl_xor(a0, 32);
            a1 += __shfl_xor(a1, 16); a1 += __shfl_xor(a1, 32);
            a2 += __shfl_xor(a2, 16); a2 += __shfl_xor(a2, 32);
            a3 += __shfl_xor(a3, 16); a3 += __shfl_xor(a3, 32);
        }
        if (q == 0) {
            float dv = fmaxf((float)dn, 1.f);
            *reinterpret_cast<float4*>(&out[(size_t)row * DD + ql * 4]) =
                make_float4(a0 / dv, a1 / dv, a2 / dv, a3 / dv);
        }
    }
}

extern "C" void kernel_launch(void* const* d_in, const int* in_sizes, int n_in,
                              void* d_out, int out_size, void* d_ws, size_t ws_size,
                              hipStream_t stream) {
    const float* x  = (const float*)d_in[0];
    const int*   ei = (const int*)d_in[1];   // [2, NE] int32
    const float* ef = (const float*)d_in[2];
    const float* We = (const float*)d_in[3];
    const float* be = (const float*)d_in[4];
    const float* Wn = (const float*)d_in[5];
    const float* bn = (const float*)d_in[6];
    float* out = (float*)d_out;

    unsigned short* xpb = (unsigned short*)d_ws;
    int*  cursor = (int*)d_ws + 3200000;
    int2* binned = (int2*)((int*)d_ws + 3202112);

    proj_kernel<<<(NN + 127) / 128, 256, 0, stream>>>(x, Wn, bn, xpb, cursor);
    binAG_kernel<<<NBLKA, 512, 0, stream>>>(ei, ef, We, be, cursor, binned);
    binB_kernel<<<NBIN, 512, 0, stream>>>(xpb, cursor, binned, out);
}